// Round 1
// baseline (272.464 us; speedup 1.0000x reference)
//
#include <hip/hip_runtime.h>

// ---------------------------------------------------------------------------
// 2-layer tanh RNN, H=4, I=2, packed-sequence masking.
// Layout: 4 lanes per batch element (lane i holds component i of h1/h2).
// Quad shuffles via DPP quad_perm. Layers software-pipelined with 1-step lag
// so L1(step t) and L2(step t-1) are independent within an iteration.
// ---------------------------------------------------------------------------

#define QP_XOR1 0xB1  // quad_perm [1,0,3,2]
#define QP_XOR2 0x4E  // quad_perm [2,3,0,1]
#define QP_XOR3 0x1B  // quad_perm [3,2,1,0]

template<int CTRL>
__device__ __forceinline__ float qperm(float x) {
    return __int_as_float(__builtin_amdgcn_mov_dpp(__float_as_int(x), CTRL, 0xF, 0xF, true));
}

__device__ __forceinline__ float tanh_fast(float x) {
    // tanh(x) = 1 - 2/(e^{2x}+1); e^{2x} = exp2(x * 2*log2(e))
    float e = __builtin_amdgcn_exp2f(x * 2.8853900817779268f);
    float r = __builtin_amdgcn_rcpf(e + 1.0f);
    return fmaf(-2.0f, r, 1.0f);
}

// Pack tokens (int32 0/1) into bitmasks: bit t%64 of word t/64 per row.
__global__ __launch_bounds__(64) void pack_kernel(const int* __restrict__ toks,
                                                  unsigned long long* __restrict__ packed) {
    int tid = blockIdx.x * 64 + threadIdx.x;
    int tok = toks[tid];
    unsigned long long m = __ballot(tok != 0);
    if ((threadIdx.x & 63) == 0) packed[tid >> 6] = m;
}

__global__ __launch_bounds__(64) void rnn_kernel(
    const unsigned* __restrict__ packed,   // [B][T/32] little-endian bit order
    const int* __restrict__ lengths,
    const float* __restrict__ W_ih0, const float* __restrict__ W_hh0,
    const float* __restrict__ b_ih0, const float* __restrict__ b_hh0,
    const float* __restrict__ W_ih1, const float* __restrict__ W_hh1,
    const float* __restrict__ b_ih1, const float* __restrict__ b_hh1,
    const float* __restrict__ h0,
    float* __restrict__ out, int T)
{
    const int lane = threadIdx.x;      // 0..63
    const int q    = lane >> 2;        // quad 0..15
    const int i    = lane & 3;         // row within H=4
    const int b    = blockIdx.x * 16 + q;
    const int Tw   = T >> 5;           // uint words per row

    // Per-lane parameters. Weight for FMA with shfl_xor(h,k) is W[i][i^k].
    float c0  = W_ih0[i*2+0] + b_ih0[i] + b_hh0[i];
    float c1  = W_ih0[i*2+1] + b_ih0[i] + b_hh0[i];
    float w0a = W_hh0[i*4 + i],     w0b = W_hh0[i*4 + (i^1)];
    float w0c = W_hh0[i*4 + (i^2)], w0d = W_hh0[i*4 + (i^3)];
    float waa = W_ih1[i*4 + i],     wab = W_ih1[i*4 + (i^1)];
    float wac = W_ih1[i*4 + (i^2)], wad = W_ih1[i*4 + (i^3)];
    float wha = W_hh1[i*4 + i],     whb = W_hh1[i*4 + (i^1)];
    float whc = W_hh1[i*4 + (i^2)], whd = W_hh1[i*4 + (i^3)];
    float b2  = b_ih1[i] + b_hh1[i];

    float h1 = h0[i];
    float h2 = h0[4 + i];
    const unsigned len = (unsigned)lengths[b];

    // wave-wide max length -> uniform loop bound
    unsigned wmax = len;
    #pragma unroll
    for (int off = 32; off; off >>= 1) {
        unsigned o = (unsigned)__shfl_xor((int)wmax, off, 64);
        wmax = wmax > o ? wmax : o;
    }

    float a1p  = 0.0f;   // layer-1 output candidate from previous iteration
    bool vprev = false;  // validity of step t-1

    const unsigned* row = packed + (size_t)b * Tw;
    unsigned wcur  = row[0];
    unsigned wnext = row[Tw > 1 ? 1 : 0];

    // iterate t = 0 .. wmax inclusive (iteration t does L1(t) and L2(t-1))
    for (unsigned t0 = 0; t0 <= wmax; t0 += 32) {
        unsigned w = wcur;
        wcur = wnext;
        unsigned nidx = (t0 >> 5) + 2;
        wnext = row[nidx < (unsigned)Tw ? nidx : (unsigned)(Tw - 1)];
        #pragma unroll
        for (int s = 0; s < 32; ++s) {
            const unsigned t = t0 + (unsigned)s;

            // ---- layer 2 for step t-1 (independent of this iter's L1) ----
            float ax1 = qperm<QP_XOR1>(a1p), ax2 = qperm<QP_XOR2>(a1p), ax3 = qperm<QP_XOR3>(a1p);
            float hx1 = qperm<QP_XOR1>(h2),  hx2 = qperm<QP_XOR2>(h2),  hx3 = qperm<QP_XOR3>(h2);
            float sA = fmaf(waa, a1p, b2);
            sA = fmaf(wab, ax1, sA);
            float sB = wac * ax2;
            sB = fmaf(wad, ax3, sB);
            float sC = wha * h2;
            sC = fmaf(whb, hx1, sC);
            float sD = whc * hx2;
            sD = fmaf(whd, hx3, sD);
            float u2 = tanh_fast((sA + sB) + (sC + sD));
            h2 = vprev ? u2 : h2;

            // ---- layer 1 for step t ----
            float c = (w & 1u) ? c1 : c0;
            w >>= 1;
            float x1 = qperm<QP_XOR1>(h1), x2 = qperm<QP_XOR2>(h1), x3 = qperm<QP_XOR3>(h1);
            float rA = fmaf(w0a, h1, c);
            rA = fmaf(w0b, x1, rA);
            float rB = w0c * x2;
            rB = fmaf(w0d, x3, rB);
            float u1 = tanh_fast(rA + rB);
            bool v = t < len;
            h1 = v ? u1 : h1;
            a1p = u1;
            vprev = v;
        }
    }
    out[b * 4 + i] = h2;
}

extern "C" void kernel_launch(void* const* d_in, const int* in_sizes, int n_in,
                              void* d_out, int out_size, void* d_ws, size_t ws_size,
                              hipStream_t stream) {
    const int*   tokens  = (const int*)d_in[0];
    const int*   lengths = (const int*)d_in[1];
    const float* W_ih0   = (const float*)d_in[2];
    const float* W_hh0   = (const float*)d_in[3];
    const float* b_ih0   = (const float*)d_in[4];
    const float* b_hh0   = (const float*)d_in[5];
    const float* W_ih1   = (const float*)d_in[6];
    const float* W_hh1   = (const float*)d_in[7];
    const float* b_ih1   = (const float*)d_in[8];
    const float* b_hh1   = (const float*)d_in[9];
    const float* h0      = (const float*)d_in[10];
    float* out = (float*)d_out;

    const int B = in_sizes[1];
    const int T = in_sizes[0] / B;

    unsigned long long* packed = (unsigned long long*)d_ws;  // B*T/8 bytes = 1 MB

    pack_kernel<<<(B * T) / 64, 64, 0, stream>>>(tokens, packed);
    rnn_kernel<<<B / 16, 64, 0, stream>>>((const unsigned*)packed, lengths,
        W_ih0, W_hh0, b_ih0, b_hh0, W_ih1, W_hh1, b_ih1, b_hh1, h0, out, T);
}

// Round 2
// 215.771 us; speedup vs baseline: 1.2627x; 1.2627x over previous
//
#include <hip/hip_runtime.h>

// ---------------------------------------------------------------------------
// 2-layer tanh RNN, H=4, I=2, packed sequences. 4 lanes per batch element.
// State transform: r = (1 - h)/2  =>  r' = rcp(1 + exp2(C + V·r)),
// V = -2*K*W, C = K*(bias + rowsum(W)...), K = 2*log2(e). This shortens the
// serial chain (no tanh epilogue, no arg scaling) and states free-run past
// len; the layer-2 candidate is snapshotted at t == len (off-chain cndmask).
// Layers pipelined with 1-step lag; L2 reuses L1's quad-perms of r1.
// ---------------------------------------------------------------------------

#define QP1 0xB1  // quad_perm [1,0,3,2]  (xor 1)
#define QP2 0x4E  // quad_perm [2,3,0,1]  (xor 2)
#define QP3 0x1B  // quad_perm [3,2,1,0]  (xor 3)

template<int C>
__device__ __forceinline__ float qp(float x) {
    return __int_as_float(__builtin_amdgcn_mov_dpp(__float_as_int(x), C, 0xF, 0xF, true));
}

// Pack tokens (int 0/1) into bitmasks, bit t%64 of word t/64 per row.
// 1024 threads/block, 16 waves, 4 ballots each -> 4096 tokens/block.
__global__ __launch_bounds__(1024) void pack_kernel(const int* __restrict__ toks,
                                                    unsigned long long* __restrict__ packed) {
    const int lane = threadIdx.x & 63;
    const int wid  = threadIdx.x >> 6;
    const long long tb = (long long)blockIdx.x * 4096 + wid * 256;
    unsigned long long w0 = __ballot(toks[tb +   0 + lane] != 0);
    unsigned long long w1 = __ballot(toks[tb +  64 + lane] != 0);
    unsigned long long w2 = __ballot(toks[tb + 128 + lane] != 0);
    unsigned long long w3 = __ballot(toks[tb + 192 + lane] != 0);
    if (lane < 4) {
        unsigned long long v = lane == 0 ? w0 : lane == 1 ? w1 : lane == 2 ? w2 : w3;
        packed[(tb >> 6) + lane] = v;
    }
}

// One step: iteration tt computes r1(tt) and r2(tt-1).
// FIRST0 (compile-time) re-initializes r2 after the throwaway tt==0 L2.
#define STEP(tt, FIRST0)                                                  \
  {                                                                       \
    float x1 = qp<QP1>(r1), x2 = qp<QP2>(r1), x3 = qp<QP3>(r1);           \
    float cc = (w & 1u) ? C1 : C0; w >>= 1;                               \
    float f1 = fmaf(v0a, r1, cc); f1 = fmaf(v0b, x1, f1);                 \
    float f2 = v0c * x2;          f2 = fmaf(v0d, x3, f2);                 \
    float e1  = __builtin_amdgcn_exp2f(f1 + f2);                          \
    float r1n = __builtin_amdgcn_rcpf(e1 + 1.0f);                         \
    float y1 = qp<QP1>(r2), y2 = qp<QP2>(r2), y3 = qp<QP3>(r2);           \
    float g1 = fmaf(vAa, r1, C2); g1 = fmaf(vAb, x1, g1);                 \
    float g2 = vAc * x2;          g2 = fmaf(vAd, x3, g2);                 \
    float g3 = vHa * r2;          g3 = fmaf(vHb, y1, g3);                 \
    float g4 = vHc * y2;          g4 = fmaf(vHd, y3, g4);                 \
    float e2  = __builtin_amdgcn_exp2f((g1 + g2) + (g3 + g4));            \
    float r2n = __builtin_amdgcn_rcpf(e2 + 1.0f);                         \
    save = ((tt) == len) ? r2n : save;                                    \
    r1 = r1n;                                                             \
    r2 = (FIRST0) ? r2i : r2n;                                            \
  }

__global__ __launch_bounds__(64) void rnn_kernel(
    const unsigned* __restrict__ packed,   // [B][T/32]
    const int* __restrict__ lengths,
    const float* __restrict__ W_ih0, const float* __restrict__ W_hh0,
    const float* __restrict__ b_ih0, const float* __restrict__ b_hh0,
    const float* __restrict__ W_ih1, const float* __restrict__ W_hh1,
    const float* __restrict__ b_ih1, const float* __restrict__ b_hh1,
    const float* __restrict__ h0,
    float* __restrict__ out, int T)
{
    const int lane = threadIdx.x;
    const int q    = lane >> 2;
    const int i    = lane & 3;
    const int b    = blockIdx.x * 16 + q;
    const int Tw   = T >> 5;

    const float K  = 2.8853900817779268f;   // 2*log2(e)
    const float NK = -2.0f * K;

    float rs0 = W_hh0[i*4+0] + W_hh0[i*4+1] + W_hh0[i*4+2] + W_hh0[i*4+3];
    float cb0 = b_ih0[i] + b_hh0[i] + rs0;
    float C0  = K * (W_ih0[i*2+0] + cb0);
    float C1  = K * (W_ih0[i*2+1] + cb0);
    float v0a = NK * W_hh0[i*4 + i],     v0b = NK * W_hh0[i*4 + (i^1)];
    float v0c = NK * W_hh0[i*4 + (i^2)], v0d = NK * W_hh0[i*4 + (i^3)];

    float rsA = W_ih1[i*4+0] + W_ih1[i*4+1] + W_ih1[i*4+2] + W_ih1[i*4+3];
    float rsH = W_hh1[i*4+0] + W_hh1[i*4+1] + W_hh1[i*4+2] + W_hh1[i*4+3];
    float C2  = K * (b_ih1[i] + b_hh1[i] + rsA + rsH);
    float vAa = NK * W_ih1[i*4 + i],     vAb = NK * W_ih1[i*4 + (i^1)];
    float vAc = NK * W_ih1[i*4 + (i^2)], vAd = NK * W_ih1[i*4 + (i^3)];
    float vHa = NK * W_hh1[i*4 + i],     vHb = NK * W_hh1[i*4 + (i^1)];
    float vHc = NK * W_hh1[i*4 + (i^2)], vHd = NK * W_hh1[i*4 + (i^3)];

    float r1  = fmaf(-0.5f, h0[i],     0.5f);   // r = (1-h)/2
    float r2i = fmaf(-0.5f, h0[4 + i], 0.5f);
    float r2  = r2i;
    float save = r2i;
    const int len = lengths[b];

    // wave-wide max length -> uniform loop bound
    int wmax = len;
    #pragma unroll
    for (int off = 32; off; off >>= 1) {
        int o = __shfl_xor(wmax, off, 64);
        wmax = wmax > o ? wmax : o;
    }

    const unsigned* row = packed + (size_t)b * Tw;
    unsigned wcur  = row[0];
    unsigned wnext = row[1 < Tw ? 1 : Tw - 1];

    // word 0 (iterations 0..31); s==0 performs the pipeline-fill L1 and
    // discards the throwaway L2 output (r2 reset to r2i).
    {
        unsigned w = wcur;
        wcur  = wnext;
        wnext = row[2 < Tw ? 2 : Tw - 1];
        #pragma unroll
        for (int s = 0; s < 32; ++s) {
            STEP(s, s == 0)
        }
    }
    for (int t0 = 32; t0 <= wmax; t0 += 32) {
        unsigned w = wcur;
        wcur = wnext;
        int nidx = (t0 >> 5) + 2;
        wnext = row[nidx < Tw ? nidx : Tw - 1];
        #pragma unroll
        for (int s = 0; s < 32; ++s) {
            STEP(t0 + s, false)
        }
    }

    out[b * 4 + i] = fmaf(-2.0f, save, 1.0f);
}

extern "C" void kernel_launch(void* const* d_in, const int* in_sizes, int n_in,
                              void* d_out, int out_size, void* d_ws, size_t ws_size,
                              hipStream_t stream) {
    const int*   tokens  = (const int*)d_in[0];
    const int*   lengths = (const int*)d_in[1];
    const float* W_ih0   = (const float*)d_in[2];
    const float* W_hh0   = (const float*)d_in[3];
    const float* b_ih0   = (const float*)d_in[4];
    const float* b_hh0   = (const float*)d_in[5];
    const float* W_ih1   = (const float*)d_in[6];
    const float* W_hh1   = (const float*)d_in[7];
    const float* b_ih1   = (const float*)d_in[8];
    const float* b_hh1   = (const float*)d_in[9];
    const float* h0      = (const float*)d_in[10];
    float* out = (float*)d_out;

    const int B = in_sizes[1];
    const int T = in_sizes[0] / B;

    unsigned long long* packed = (unsigned long long*)d_ws;  // B*T/8 bytes

    pack_kernel<<<(B * T) / 4096, 1024, 0, stream>>>(tokens, packed);
    rnn_kernel<<<B / 16, 64, 0, stream>>>((const unsigned*)packed, lengths,
        W_ih0, W_hh0, b_ih0, b_hh0, W_ih1, W_hh1, b_ih1, b_hh1, h0, out, T);
}